// Round 2
// baseline (825.384 us; speedup 1.0000x reference)
//
#include <hip/hip_runtime.h>
#include <stdint.h>

typedef unsigned short u16;
typedef __bf16 bf16x8 __attribute__((ext_vector_type(8)));
typedef float f32x4 __attribute__((ext_vector_type(4)));

#define HID 512
#define BATCH 32
#define SEQ 2048
#define NLAYERS 4
#define BT (BATCH*SEQ)
#define CHUNKS 64
#define TC (SEQ/CHUNKS)

__device__ __forceinline__ float bf2f(uint32_t lo) {
  union { uint32_t u; float f; } c; c.u = lo << 16; return c.f;
}
__device__ __forceinline__ uint32_t f2bf(float f) {
  union { float f; uint32_t u; } c; c.f = f;
  return (c.u + 0x7fffu + ((c.u >> 16) & 1u)) >> 16;  // RNE
}
__device__ __forceinline__ float fast_rcp(float x) { return __builtin_amdgcn_rcpf(x); }

// async global->LDS, 16B per lane; LDS dest is wave-uniform base + lane*16
__device__ __forceinline__ void gload_lds16(const u16* g, u16* l) {
  __builtin_amdgcn_global_load_lds((__attribute__((address_space(1))) void*)g,
                                   (__attribute__((address_space(3))) void*)l, 16, 0, 0);
}

// ---------------- weight transpose+convert: Wt[l][n][k] = (n<512?Wz:Wh)[l][k][n%512], bf16
__global__ __launch_bounds__(256) void conv_weights(const float* __restrict__ Wz,
                                                    const float* __restrict__ Wh,
                                                    u16* __restrict__ Wt) {
  __shared__ float tile[64][65];
  const int l = blockIdx.z;
  const int k0 = blockIdx.x * 64;
  const int n0 = blockIdx.y * 64;
  const float* W = (n0 < 512 ? Wz : Wh) + (size_t)l * HID * HID;
  const int nc0 = (n0 < 512) ? n0 : n0 - 512;
  const int tx = threadIdx.x & 63, ty = threadIdx.x >> 6;
  for (int r = ty; r < 64; r += 4) tile[r][tx] = W[(size_t)(k0 + r) * HID + nc0 + tx];
  __syncthreads();
  for (int r = ty; r < 64; r += 4)
    Wt[((size_t)l * 1024 + n0 + r) * HID + k0 + tx] = (u16)f2bf(tile[tx][r]);
}

// ---------------- x -> bf16
__global__ __launch_bounds__(256) void conv_x(const float* __restrict__ x, u16* __restrict__ xb) {
  size_t i = ((size_t)blockIdx.x * 256 + threadIdx.x) * 4;
  float4 f = *(const float4*)(x + i);
  uint2 o;
  o.x = f2bf(f.x) | (f2bf(f.y) << 16);
  o.y = f2bf(f.z) | (f2bf(f.w) << 16);
  *(uint2*)(xb + i) = o;
}

// ---------------- fused GEMM: [k | hh] = cur @ [Wz | Wh] + bias -> packed (a,v) bf16
// 256x256-tile, BK=64, 8 waves, 8-phase schedule with counted vmcnt (guide §5 template),
// XOR-swizzled LDS (inverse-swizzled global src + swizzled ds_read; linear gload_lds dest),
// fused chunk-local scan composition (Ac, Bc) in the epilogue.
// XCD mapping: mt = (r>>2)*8 + (bid&7), nt = r&3  -> the 4 n-blocks of one m-tile run
// concurrently on ONE XCD -> A panel fetched from HBM once.
__global__ __launch_bounds__(512) void gemm_av(const u16* __restrict__ Ab,
                                               const u16* __restrict__ Btw,
                                               const float* __restrict__ bz,
                                               const float* __restrict__ bhp,
                                               uint32_t* __restrict__ av,
                                               float* __restrict__ Ac,
                                               float* __restrict__ Bc) {
  __shared__ __align__(16) u16 As[2][2][8192];   // [dbuf][half][128 rows x 64 k], 16KB each
  __shared__ __align__(16) u16 Bs[2][2][8192];

  const int bid = blockIdx.x;
  const int xcd = bid & 7, rr_ = bid >> 3;
  const int mt = (rr_ >> 2) * 8 + xcd;     // 0..255
  const int nt = rr_ & 3;                  // 0..3
  const int m0 = mt * 256;

  const int tid = threadIdx.x;
  const int lane = tid & 63, wv = tid >> 6;
  const int wm = wv >> 2, wn = wv & 3;     // 2 x 4 wave grid
  const int l15 = lane & 15, quad = lane >> 4;
  const int rx = l15 & 7;
  const int bhalf = wn >> 1;

  // ds_read offsets (u16 units) within a half: row*64 + swz_slot*8
  const int aro0 = l15 * 64 + ((quad ^ rx) * 8);
  const int aro1 = l15 * 64 + (((4 + quad) ^ rx) * 8);
  const int bro0 = ((wn & 1) * 64 + l15) * 64 + ((quad ^ rx) * 8);
  const int bro1 = ((wn & 1) * 64 + l15) * 64 + (((4 + quad) ^ rx) * 8);

  // staging: per call 512 threads x 16B = 64 rows; wave wv -> rows [wv*8, wv*8+8)
  // global source pre-swizzled so linear LDS holds swizzled layout (rule #21)
  const int srow = tid >> 3;                        // 0..63
  const int kslot = (lane & 7) ^ (srow & 7);        // inverse swizzle (involution)
  const u16* aS = Ab + (size_t)(m0 + srow) * HID + kslot * 8;
  const int qb = (srow >> 5) & 1, jb = srow & 31;
  const u16* bS = Btw + (size_t)(qb * 512 + nt * 128 + jb) * HID + kslot * 8;

  f32x4 acc[8][4];
#pragma unroll
  for (int i = 0; i < 8; ++i)
#pragma unroll
    for (int j = 0; j < 4; ++j) acc[i][j] = (f32x4){0.f, 0.f, 0.f, 0.f};
  bf16x8 afr[4][2], bfr[4][2];

#define STG_A(T, H, D) if ((T) < 8) { \
    gload_lds16(aS + (size_t)((H)*65536 + (T)*64), &As[D][H][wv*512]); \
    gload_lds16(aS + (size_t)((H)*65536 + 32768 + (T)*64), &As[D][H][4096 + wv*512]); }
#define STG_B(T, H, D) if ((T) < 8) { \
    gload_lds16(bS + (size_t)((H)*32768 + (T)*64), &Bs[D][H][wv*512]); \
    gload_lds16(bS + (size_t)((H)*32768 + 16384 + (T)*64), &Bs[D][H][4096 + wv*512]); }
#define LDA4(D, MB) { \
    _Pragma("unroll") for (int m_ = 0; m_ < 4; ++m_) \
    _Pragma("unroll") for (int k_ = 0; k_ < 2; ++k_) \
      afr[m_][k_] = *(const bf16x8*)&As[D][wm][((MB)+m_)*1024 + (k_ ? aro1 : aro0)]; }
#define LDB2(D, NB) { \
    _Pragma("unroll") for (int n_ = 0; n_ < 2; ++n_) \
    _Pragma("unroll") for (int k_ = 0; k_ < 2; ++k_) \
      bfr[(NB)+n_][k_] = *(const bf16x8*)&Bs[D][bhalf][((NB)+n_)*1024 + (k_ ? bro1 : bro0)]; }
#define QUAD(MB, NB) { \
    _Pragma("unroll") for (int k_ = 0; k_ < 2; ++k_) \
    _Pragma("unroll") for (int m_ = 0; m_ < 4; ++m_) \
    _Pragma("unroll") for (int n_ = 0; n_ < 2; ++n_) \
      acc[(MB)+m_][(NB)+n_] = __builtin_amdgcn_mfma_f32_16x16x32_bf16( \
          afr[m_][k_], bfr[(NB)+n_][k_], acc[(MB)+m_][(NB)+n_], 0, 0, 0); }
#define PH_MID \
    __builtin_amdgcn_s_barrier(); \
    asm volatile("s_waitcnt lgkmcnt(0)" ::: "memory"); \
    __builtin_amdgcn_sched_barrier(0); \
    __builtin_amdgcn_s_setprio(1);
#define PH_END \
    __builtin_amdgcn_s_setprio(0); \
    __builtin_amdgcn_s_barrier(); \
    __builtin_amdgcn_sched_barrier(0);
#define PH_END_VM(N) \
    __builtin_amdgcn_s_setprio(0); \
    asm volatile("s_waitcnt vmcnt(" #N ")" ::: "memory"); \
    __builtin_amdgcn_s_barrier(); \
    __builtin_amdgcn_sched_barrier(0);

  // prologue: tile0 (A+B, buf0) + tile1 B (buf1) = 12 loads; wait oldest 8 (= tile0)
  STG_A(0, 0, 0); STG_A(0, 1, 0);
  STG_B(0, 0, 0); STG_B(0, 1, 0);
  STG_B(1, 0, 1); STG_B(1, 1, 1);
  asm volatile("s_waitcnt vmcnt(4)" ::: "memory");
  __builtin_amdgcn_s_barrier();
  __builtin_amdgcn_sched_barrier(0);

#pragma unroll
  for (int it = 0; it < 4; ++it) {
    const int ta = 2 * it, tb = 2 * it + 1;
    // P0: reads tile ta (A m0-3, B n0-1) | stage A(tb) h0 -> buf1
    LDA4(0, 0); LDB2(0, 0); STG_A(tb, 0, 1);
    PH_MID; QUAD(0, 0); PH_END;
    // P1: reads B n2-3 | stage A(tb) h1
    LDB2(0, 2); STG_A(tb, 1, 1);
    PH_MID; QUAD(0, 2); PH_END;
    // P2: reads A m4-7 | stage B(ta+2) h0 -> buf0
    LDA4(0, 4); STG_B(ta + 2, 0, 0);
    PH_MID; QUAD(4, 0); PH_END;
    // P3: stage B(ta+2) h1 | tail vmcnt guarantees tile tb landed before P4 reads
    STG_B(ta + 2, 1, 0);
    PH_MID; QUAD(4, 2);
    if (it == 3) { PH_END_VM(0); } else { PH_END_VM(4); }
    // P4: reads tile tb (buf1) | stage A(ta+2) h0 -> buf0
    LDA4(1, 0); LDB2(1, 0); STG_A(ta + 2, 0, 0);
    PH_MID; QUAD(0, 0); PH_END;
    // P5
    LDB2(1, 2); STG_A(ta + 2, 1, 0);
    PH_MID; QUAD(0, 2); PH_END;
    // P6
    LDA4(1, 4); STG_B(tb + 2, 0, 1);
    PH_MID; QUAD(4, 0); PH_END;
    // P7: tail vmcnt guarantees tile ta+2 landed before next iter's P0 reads
    STG_B(tb + 2, 1, 1);
    PH_MID; QUAD(4, 2); PH_END_VM(4);
  }

  // ---- epilogue: activations -> packed av + per-chunk (A,B) scan composition.
  // C/D layout: col=lane&15, row=quad*4+reg. acc[mf][0..1]=k(Wz), acc[mf][2..3]=hh(Wh),
  // same output column for nf and nf+2. Wave rows: wm*128 + mf*16; chunk = mf pair.
  const int colbase = nt * 128 + wn * 32;
  float bzv[2], bhv[2];
#pragma unroll
  for (int nf = 0; nf < 2; ++nf) {
    bzv[nf] = bz[colbase + nf * 16 + l15];
    bhv[nf] = bhp[colbase + nf * 16 + l15];
  }
  const int wrow0 = m0 + wm * 128;
  const int bb = wrow0 >> 11;
#pragma unroll
  for (int c = 0; c < 4; ++c) {
    const int cc = ((wrow0 + c * 32) & 2047) >> 5;
    const size_t abase = (size_t)(bb * CHUNKS + cc) * HID;
#pragma unroll
    for (int nf = 0; nf < 2; ++nf) {
      const int col = colbase + nf * 16 + l15;
      float Aseg[2], Bseg[2];
#pragma unroll
      for (int hseg = 0; hseg < 2; ++hseg) {
        const int mf = 2 * c + hseg;
        const int rbase = wrow0 + mf * 16 + quad * 4;
        float A = 1.f, Bv = 0.f;
#pragma unroll
        for (int r = 0; r < 4; ++r) {
          float kv = acc[mf][nf][r] + bzv[nf];
          float hv = acc[mf][nf + 2][r] + bhv[nf];
          float e = __expf(-kv);
          float inv = fast_rcp(1.f + e);
          float a = e * inv;   // sigmoid(-k) = 1-z
          float v = inv * ((hv >= 0.f) ? (hv + 0.5f) : fast_rcp(1.f + __expf(-hv)));
          av[(size_t)(rbase + r) * HID + col] = f2bf(a) | (f2bf(v) << 16);
          A *= a;
          Bv = a * Bv + v;
        }
        Aseg[hseg] = A; Bseg[hseg] = Bv;
      }
#pragma unroll
      for (int hseg = 0; hseg < 2; ++hseg) {
        float Ap = __shfl_xor(Aseg[hseg], 16), Bp = __shfl_xor(Bseg[hseg], 16);
        float Ae = (quad & 1) ? Ap : Aseg[hseg], Be = (quad & 1) ? Bp : Bseg[hseg];
        float Al = (quad & 1) ? Aseg[hseg] : Ap, Bl = (quad & 1) ? Bseg[hseg] : Bp;
        Aseg[hseg] = Al * Ae; Bseg[hseg] = Al * Be + Bl;
        Ap = __shfl_xor(Aseg[hseg], 32); Bp = __shfl_xor(Bseg[hseg], 32);
        Ae = (quad & 2) ? Ap : Aseg[hseg]; Be = (quad & 2) ? Bp : Bseg[hseg];
        Al = (quad & 2) ? Aseg[hseg] : Ap; Bl = (quad & 2) ? Bseg[hseg] : Bp;
        Aseg[hseg] = Al * Ae; Bseg[hseg] = Al * Be + Bl;
      }
      float CA = Aseg[1] * Aseg[0];
      float CB = Aseg[1] * Bseg[0] + Bseg[1];
      if (quad == 0) {
        Ac[abase + col] = CA;
        Bc[abase + col] = CB;
      }
    }
  }
#undef STG_A
#undef STG_B
#undef LDA4
#undef LDB2
#undef QUAD
#undef PH_MID
#undef PH_END
#undef PH_END_VM
}

// ---------------- phase 2: sequential over chunks; also emits h[T-1] (hiddens output)
__global__ __launch_bounds__(256) void scan_boundary(const float* __restrict__ Ac,
                                                     const float* __restrict__ Bc,
                                                     const float* __restrict__ h0,
                                                     float* __restrict__ hinit,
                                                     float* __restrict__ hid_out) {
  const int idx = blockIdx.x * 256 + threadIdx.x;  // b*HID + h
  const int b = idx >> 9, h = idx & 511;
  float x0 = h0[idx];
  float hr = (x0 >= 0.f) ? (x0 + 0.5f) : fast_rcp(1.f + __expf(-x0));  // g(h0)
  for (int c = 0; c < CHUNKS; ++c) {
    size_t o = ((size_t)(b * CHUNKS + c)) * HID + h;
    hinit[o] = hr;
    hr = Ac[o] * hr + Bc[o];
  }
  hid_out[idx] = hr;
}

// ---------------- phase 3: apply scan + LayerNorm + residual.
__global__ __launch_bounds__(512) void scan_apply(const uint32_t* av,  // may alias outf
                                                  const float* __restrict__ hinit,
                                                  const u16* __restrict__ resb,
                                                  const float* __restrict__ gamma,
                                                  const float* __restrict__ beta,
                                                  u16* outb, float* outf) {
  __shared__ float hbuf[TC][HID];   // exactly 64 KB
  const int b = blockIdx.y, c = blockIdx.x, h = threadIdx.x;
  const int lane = h & 63, wv = h >> 6;
  const size_t rowbase = (size_t)(b * SEQ + c * TC) * HID;

  // pass 1: sequential scan along t, thread pinned to channel h
  float hr = hinit[((size_t)(b * CHUNKS + c)) * HID + h];
#pragma unroll 8
  for (int t = 0; t < TC; ++t) {
    uint32_t p = av[rowbase + (size_t)t * HID + h];
    hr = bf2f(p & 0xffffu) * hr + bf2f(p >> 16);
    hbuf[t][h] = hr;
  }
  __syncthreads();

  // pass 2: wave wv handles t = wv*4 + i; lane covers h = lane*8..lane*8+7
  const int h0c = lane * 8;
  const f32x4 gm0 = *(const f32x4*)&gamma[h0c];
  const f32x4 gm1 = *(const f32x4*)&gamma[h0c + 4];
  const f32x4 be0 = *(const f32x4*)&beta[h0c];
  const f32x4 be1 = *(const f32x4*)&beta[h0c + 4];
#pragma unroll
  for (int i = 0; i < 4; ++i) {
    const int t = wv * 4 + i;
    f32x4 v0 = *(const f32x4*)&hbuf[t][h0c];
    f32x4 v1 = *(const f32x4*)&hbuf[t][h0c + 4];
    float s = v0[0] + v0[1] + v0[2] + v0[3] + v1[0] + v1[1] + v1[2] + v1[3];
    float q = v0[0]*v0[0] + v0[1]*v0[1] + v0[2]*v0[2] + v0[3]*v0[3]
            + v1[0]*v1[0] + v1[1]*v1[1] + v1[2]*v1[2] + v1[3]*v1[3];
#pragma unroll
    for (int d = 32; d; d >>= 1) { s += __shfl_xor(s, d); q += __shfl_xor(q, d); }
    const float mu = s * (1.f / HID);
    const float rs = rsqrtf(q * (1.f / HID) - mu * mu + 1e-5f);
    // residual (bf16, 8 lanes' worth in 16B)
    const size_t o = rowbase + (size_t)t * HID + h0c;
    uint4 rr = *(const uint4*)(resb + o);
    float y[8];
    const uint32_t rw[4] = {rr.x, rr.y, rr.z, rr.w};
#pragma unroll
    for (int j = 0; j < 8; ++j) {
      float hv = (j < 4) ? v0[j] : v1[j - 4];
      float gmv = (j < 4) ? gm0[j] : gm1[j - 4];
      float bev = (j < 4) ? be0[j] : be1[j - 4];
      float rv = bf2f((rw[j >> 1] >> ((j & 1) * 16)) & 0xffffu);
      y[j] = (hv - mu) * rs * gmv + bev + rv;
    }
    if (outb) {
      uint4 ob;
      ob.x = f2bf(y[0]) | (f2bf(y[1]) << 16);
      ob.y = f2bf(y[2]) | (f2bf(y[3]) << 16);
      ob.z = f2bf(y[4]) | (f2bf(y[5]) << 16);
      ob.w = f2bf(y[6]) | (f2bf(y[7]) << 16);
      *(uint4*)(outb + o) = ob;
    }
    if (outf) {
      f32x4 o0 = {y[0], y[1], y[2], y[3]}, o1 = {y[4], y[5], y[6], y[7]};
      *(f32x4*)(outf + o) = o0;
      *(f32x4*)(outf + o + 4) = o1;
    }
  }
}

extern "C" void kernel_launch(void* const* d_in, const int* in_sizes, int n_in,
                              void* d_out, int out_size, void* d_ws, size_t ws_size,
                              hipStream_t stream) {
  (void)in_sizes; (void)n_in; (void)out_size; (void)ws_size;
  const float* x     = (const float*)d_in[0];
  const float* h0    = (const float*)d_in[1];
  const float* Wz    = (const float*)d_in[2];
  const float* bz    = (const float*)d_in[3];
  const float* Wh    = (const float*)d_in[4];
  const float* bh    = (const float*)d_in[5];
  const float* gamma = (const float*)d_in[6];
  const float* beta  = (const float*)d_in[7];

  float* outf = (float*)d_out;                   // [BT*HID] cur, then [L*B*H] hiddens
  uint32_t* av = (uint32_t*)d_out;               // alias: cur region free until last apply

  char* ws = (char*)d_ws;
  u16* curb = (u16*)ws;                                   size_t off = (size_t)BT * HID * 2;
  u16* Wt = (u16*)(ws + off);                             off += (size_t)NLAYERS * 1024 * HID * 2;
  float* Ac = (float*)(ws + off);                         off += (size_t)BATCH * CHUNKS * HID * 4;
  float* Bc = (float*)(ws + off);                         off += (size_t)BATCH * CHUNKS * HID * 4;
  float* hinit = (float*)(ws + off);                      // total ~80 MB

  hipLaunchKernelGGL(conv_weights, dim3(8, 16, NLAYERS), dim3(256), 0, stream, Wz, Wh, Wt);
  hipLaunchKernelGGL(conv_x, dim3(BT * HID / 1024), dim3(256), 0, stream, x, curb);

  for (int l = 0; l < NLAYERS; ++l) {
    const bool last = (l == NLAYERS - 1);
    hipLaunchKernelGGL(gemm_av, dim3(1024), dim3(512), 0, stream,
                       curb, Wt + (size_t)l * 1024 * HID, bz + l * HID, bh + l * HID,
                       av, Ac, Bc);
    hipLaunchKernelGGL(scan_boundary, dim3(BATCH * HID / 256), dim3(256), 0, stream,
                       Ac, Bc, h0 + (size_t)l * BATCH * HID, hinit,
                       outf + (size_t)BT * HID + (size_t)l * BATCH * HID);
    hipLaunchKernelGGL(scan_apply, dim3(CHUNKS, BATCH), dim3(512), 0, stream,
                       av, hinit, curb, gamma + l * HID, beta + l * HID,
                       last ? nullptr : curb, last ? outf : nullptr);
  }
}